// Round 1
// baseline (5584.803 us; speedup 1.0000x reference)
//
#include <hip/hip_runtime.h>
#include <hip/hip_fp16.h>
#include <stdint.h>

#define SEQ 512
#define HIDN 512

typedef _Float16 h2_t __attribute__((ext_vector_type(2)));
typedef _Float16 h8_t __attribute__((ext_vector_type(8)));
typedef float f4_t __attribute__((ext_vector_type(4)));

__device__ __forceinline__ float fdot2f(uint32_t a, uint32_t b, float c) {
#if __has_builtin(__builtin_amdgcn_fdot2)
  return __builtin_amdgcn_fdot2(__builtin_bit_cast(h2_t, a),
                                __builtin_bit_cast(h2_t, b), c, false);
#else
  h2_t ah = __builtin_bit_cast(h2_t, a);
  h2_t bh = __builtin_bit_cast(h2_t, b);
  return c + (float)ah.x * (float)bh.x + (float)ah.y * (float)bh.y;
#endif
}

// ---------------- fp32 -> fp16 convert (contiguous) ----------------
__global__ void k_cvt(const float4* __restrict__ src, __half2* __restrict__ dst, int n4) {
  int i = blockIdx.x * blockDim.x + threadIdx.x;
  if (i < n4) {
    float4 v = src[i];
    dst[2 * i]     = __floats2half2_rn(v.x, v.y);
    dst[2 * i + 1] = __floats2half2_rn(v.z, v.w);
  }
}

// ---------------- transpose + convert: dst[c][r] = (half)src[r][c] ----------------
__global__ void k_transpose_cvt(const float* __restrict__ src, __half* __restrict__ dst,
                                int R, int C) {
  __shared__ float tile[32][33];
  int tx = threadIdx.x, ty = threadIdx.y;
  int c0 = blockIdx.x * 32, r0 = blockIdx.y * 32;
#pragma unroll
  for (int i = 0; i < 4; ++i)
    tile[ty + i * 8][tx] = src[(size_t)(r0 + ty + i * 8) * C + c0 + tx];
  __syncthreads();
#pragma unroll
  for (int i = 0; i < 4; ++i)
    dst[(size_t)(c0 + ty + i * 8) * R + r0 + tx] = __float2half(tile[tx][ty + i * 8]);
}

// ---------------- f16 MFMA GEMM: C(MxN,f32) = A(MxK,f16) * Bt(NxK,f16)^T + bias ----------------
__global__ __launch_bounds__(256, 2) void k_gemm(
    const __half* __restrict__ A, const __half* __restrict__ Bt,
    const float* __restrict__ bias, float* __restrict__ C,
    int M, int N, int K) {
  __shared__ __align__(16) __half As[128 * 32];
  __shared__ __align__(16) __half Bs[128 * 32];
  const int tid = threadIdx.x;
  const int m0 = blockIdx.x * 128;
  const int n0 = blockIdx.y * 128;
  const int w = tid >> 6;
  const int lane = tid & 63;
  const int wm = (w >> 1) * 64;
  const int wn = (w & 1) * 64;
  const int fr = lane & 15;
  const int q = lane >> 4;
  const int lr = tid >> 2;
  const int lc = tid & 3;
  f4_t acc[4][4];
#pragma unroll
  for (int i = 0; i < 4; ++i)
#pragma unroll
    for (int jj = 0; jj < 4; ++jj) acc[i][jj] = (f4_t)(0.f);

  for (int kk = 0; kk < K; kk += 32) {
    *(uint4*)&As[lr * 32 + lc * 8]        = *(const uint4*)&A[(size_t)(m0 + lr) * K + kk + lc * 8];
    *(uint4*)&As[(64 + lr) * 32 + lc * 8] = *(const uint4*)&A[(size_t)(m0 + 64 + lr) * K + kk + lc * 8];
    *(uint4*)&Bs[lr * 32 + lc * 8]        = *(const uint4*)&Bt[(size_t)(n0 + lr) * K + kk + lc * 8];
    *(uint4*)&Bs[(64 + lr) * 32 + lc * 8] = *(const uint4*)&Bt[(size_t)(n0 + 64 + lr) * K + kk + lc * 8];
    __syncthreads();
    h8_t af[4], bf[4];
#pragma unroll
    for (int i = 0; i < 4; ++i) {
      af[i] = *(const h8_t*)&As[(wm + i * 16 + fr) * 32 + q * 8];
      bf[i] = *(const h8_t*)&Bs[(wn + i * 16 + fr) * 32 + q * 8];
    }
#pragma unroll
    for (int i = 0; i < 4; ++i)
#pragma unroll
      for (int jj = 0; jj < 4; ++jj)
        acc[i][jj] = __builtin_amdgcn_mfma_f32_16x16x32_f16(af[i], bf[jj], acc[i][jj], 0, 0, 0);
    __syncthreads();
  }
#pragma unroll
  for (int i = 0; i < 4; ++i) {
    const int row0 = m0 + wm + i * 16 + q * 4;
#pragma unroll
    for (int jj = 0; jj < 4; ++jj) {
      const int col = n0 + wn + jj * 16 + fr;
      const float bv = bias[col];
#pragma unroll
      for (int r = 0; r < 4; ++r)
        C[(size_t)(row0 + r) * N + col] = acc[i][jj][r] + bv;
    }
  }
}

// ---------------- serial recurrence: 256 blocks x 256 threads ----------------
// 4 CUs per (b,d): group g = blockIdx&63 = (b,d); slice s = blockIdx>>6 owns
// 128 columns. Blocks of a group are stride-64 apart -> same XCD under
// round-robin dispatch (latency heuristic; correctness comes from scoped
// atomics). Thread = (col, khalf): 32 uint4 of WhT in REGISTERS (no LDS weight
// streaming at all). Per step:
//   dot(256 K-elems, 128 fdot2) -> shfl_xor(1) pair-reduce -> tanh ->
//   store 128-col h slice to global double buffer -> __syncthreads (drains all
//   waves' stores) -> one release atomicAdd(agent) per block on group counter
//   -> spin (relaxed agent load) until all 4 blocks posted -> acquire fence ->
//   reload full 1KB h from L2.
// Residency: 256 blocks x 4 waves = 1024 waves << 8192 device slots; the 96KB
// LDS pad forces 1 block/CU so each group has 4 dedicated CUs.
__global__ __launch_bounds__(256, 1) void k_rnn(
    const __half* __restrict__ WhT_f, const __half* __restrict__ WhT_b,
    const float* __restrict__ A_f, const float* __restrict__ A_b,
    __half* __restrict__ bi, __half* __restrict__ hx, uint32_t* __restrict__ cnt) {
  __shared__ char xpad[98304];                     // occupancy clamp: 1 block/CU
  if (threadIdx.x == 0) ((volatile char*)xpad)[0] = 0;

  const int g = blockIdx.x & 63;                   // (b,d) group
  const int s = blockIdx.x >> 6;                   // column slice 0..3
  const int b = g >> 1;
  const int d = g & 1;
  const int t = threadIdx.x;
  const int lane = t & 63;
  const int w = t >> 6;
  const int col = s * 128 + w * 32 + (lane >> 1);  // output column
  const int kp = lane & 1;                         // K half: elems [kp*256, kp*256+256)

  const __half* WhT = d ? WhT_b : WhT_f;           // WhT[j][k] = Wh[k][j]
  const float* A = (d ? A_b : A_f) + (size_t)b * SEQ * HIDN;
  __half* hxg = hx + (size_t)g * 2 * HIDN;         // [parity][512]
  uint32_t* cg = cnt + (size_t)g * 32;             // 128B-padded group counter
  __half* bip = bi + (size_t)b * SEQ * 1024 + (size_t)d * HIDN + col;

  // all weights register-resident: 32 uint4 = 128 VGPRs
  const uint4* wrow = (const uint4*)(WhT + (size_t)col * HIDN) + kp * 32;
  uint4 wv[32];
#pragma unroll
  for (int i = 0; i < 32; ++i) wv[i] = wrow[i];

  const int tstep = d ? -1 : 1;
  int tt = d ? (SEQ - 1) : 0;
  float a_cur = A[(size_t)tt * HIDN + col];
  float dot = 0.f;                                 // h_0 = 0

  for (int st = 0; st < SEQ; ++st) {
    // h_{st+1}[col] = tanh(dot + a)
    float p = dot + a_cur;
    float ap = fabsf(p);
    float e = __expf(2.f * ap);
    float th = 1.f - 2.f * __builtin_amdgcn_rcpf(e + 1.f);
    float h = copysignf(th, p);
    __half hh = __float2half(h);
    const int par = (st + 1) & 1;
    if (!kp) {
      hxg[par * HIDN + col] = hh;                  // publish slice (256B/block)
      bip[(size_t)tt * 1024] = hh;                 // output row
    }
    if (st == SEQ - 1) break;
    __syncthreads();                               // drains every wave's stores (vmcnt 0)
    if (t == 0)                                    // release: flushes block's stores to agent scope
      __hip_atomic_fetch_add(cg, 1u, __ATOMIC_RELEASE, __HIP_MEMORY_SCOPE_AGENT);
    tt += tstep;
    a_cur = A[(size_t)tt * HIDN + col];            // prefetch next additive term during spin
    const uint32_t target = 4u * (uint32_t)(st + 1);
    while (__hip_atomic_load(cg, __ATOMIC_RELAXED, __HIP_MEMORY_SCOPE_AGENT) < target) {}
    __builtin_amdgcn_fence(__ATOMIC_ACQUIRE, "agent");  // invalidate stale lines before h reload
    // reload full h_{st+1}: 32 x dwordx4, 2 address streams per wave (L2-resident)
    const uint4* hp = (const uint4*)(hxg + par * HIDN) + kp * 32;
    float c0 = 0.f, c1 = 0.f, c2 = 0.f, c3 = 0.f;
#pragma unroll
    for (int i = 0; i < 32; ++i) {
      uint4 hv = hp[i];
      c0 = fdot2f(hv.x, wv[i].x, c0);
      c1 = fdot2f(hv.y, wv[i].y, c1);
      c2 = fdot2f(hv.z, wv[i].z, c2);
      c3 = fdot2f(hv.w, wv[i].w, c3);
    }
    float part = (c0 + c1) + (c2 + c3);
    dot = part + __shfl_xor(part, 1, 64);          // combine K halves (same order as before)
  }
}

extern "C" void kernel_launch(void* const* d_in, const int* in_sizes, int n_in,
                              void* d_out, int out_size, void* d_ws, size_t ws_size,
                              hipStream_t stream) {
  const float* input_seq = (const float*)d_in[0];  // (32,512,512)
  const float* W_f = (const float*)d_in[1];        // (1024,512)
  const float* b_f = (const float*)d_in[2];
  const float* W_b = (const float*)d_in[3];
  const float* b_b = (const float*)d_in[4];
  const float* W_o = (const float*)d_in[5];        // (1024,512)
  const float* b_o = (const float*)d_in[6];
  float* out = (float*)d_out;

  char* ws = (char*)d_ws;
  __half* Xh    = (__half*)(ws);                    // 16 MB  (16384x512 f16)
  float*  A_f   = (float*)(ws + 16777216);          // 32 MB
  float*  A_b   = (float*)(ws + 50331648);          // 32 MB
  __half* bi    = (__half*)(ws + 83886080);         // 32 MB  (16384x1024 f16)
  __half* WxT_f = (__half*)(ws + 117440512);        // 512 KB
  __half* WxT_b = (__half*)(ws + 117964800);
  __half* WhT_f = (__half*)(ws + 118489088);        // 512 KB
  __half* WhT_b = (__half*)(ws + 119013376);
  __half* WoT   = (__half*)(ws + 119537664);        // 1 MB
  __half* hx    = (__half*)(ws + 120586240);        // 128 KB: 64 groups x 2 x 512 f16
  uint32_t* cnt = (uint32_t*)(ws + 120717312);      // 8 KB: 64 groups x 128 B

  hipMemsetAsync(cnt, 0, 8192, stream);             // group counters start at 0 each replay

  k_cvt<<<8192, 256, 0, stream>>>((const float4*)input_seq, (__half2*)Xh, 2097152);
  dim3 tb(32, 8);
  k_transpose_cvt<<<dim3(16, 16), tb, 0, stream>>>(W_f,          WxT_f, 512, 512);
  k_transpose_cvt<<<dim3(16, 16), tb, 0, stream>>>(W_f + 262144, WhT_f, 512, 512);
  k_transpose_cvt<<<dim3(16, 16), tb, 0, stream>>>(W_b,          WxT_b, 512, 512);
  k_transpose_cvt<<<dim3(16, 16), tb, 0, stream>>>(W_b + 262144, WhT_b, 512, 512);
  k_transpose_cvt<<<dim3(16, 32), tb, 0, stream>>>(W_o,          WoT, 1024, 512);

  k_gemm<<<dim3(128, 4), 256, 0, stream>>>(Xh, WxT_f, b_f, A_f, 16384, 512, 512);
  k_gemm<<<dim3(128, 4), 256, 0, stream>>>(Xh, WxT_b, b_b, A_b, 16384, 512, 512);

  k_rnn<<<256, 256, 0, stream>>>(WhT_f, WhT_b, A_f, A_b, bi, hx, cnt);

  k_gemm<<<dim3(128, 4), 256, 0, stream>>>(bi, WoT, b_o, out, 16384, 512, 1024);
}

// Round 2
// 1692.633 us; speedup vs baseline: 3.2995x; 3.2995x over previous
//
#include <hip/hip_runtime.h>
#include <hip/hip_fp16.h>
#include <stdint.h>

#define SEQ 512
#define HIDN 512

typedef _Float16 h2_t __attribute__((ext_vector_type(2)));
typedef _Float16 h8_t __attribute__((ext_vector_type(8)));
typedef float f4_t __attribute__((ext_vector_type(4)));

__device__ __forceinline__ float fdot2f(uint32_t a, uint32_t b, float c) {
#if __has_builtin(__builtin_amdgcn_fdot2)
  return __builtin_amdgcn_fdot2(__builtin_bit_cast(h2_t, a),
                                __builtin_bit_cast(h2_t, b), c, false);
#else
  h2_t ah = __builtin_bit_cast(h2_t, a);
  h2_t bh = __builtin_bit_cast(h2_t, b);
  return c + (float)ah.x * (float)bh.x + (float)ah.y * (float)bh.y;
#endif
}

// ---------------- fp32 -> fp16 convert (contiguous) ----------------
__global__ void k_cvt(const float4* __restrict__ src, __half2* __restrict__ dst, int n4) {
  int i = blockIdx.x * blockDim.x + threadIdx.x;
  if (i < n4) {
    float4 v = src[i];
    dst[2 * i]     = __floats2half2_rn(v.x, v.y);
    dst[2 * i + 1] = __floats2half2_rn(v.z, v.w);
  }
}

// ---------------- transpose + convert: dst[c][r] = (half)src[r][c] ----------------
__global__ void k_transpose_cvt(const float* __restrict__ src, __half* __restrict__ dst,
                                int R, int C) {
  __shared__ float tile[32][33];
  int tx = threadIdx.x, ty = threadIdx.y;
  int c0 = blockIdx.x * 32, r0 = blockIdx.y * 32;
#pragma unroll
  for (int i = 0; i < 4; ++i)
    tile[ty + i * 8][tx] = src[(size_t)(r0 + ty + i * 8) * C + c0 + tx];
  __syncthreads();
#pragma unroll
  for (int i = 0; i < 4; ++i)
    dst[(size_t)(c0 + ty + i * 8) * R + r0 + tx] = __float2half(tile[tx][ty + i * 8]);
}

// ---------------- Wh repack: chunk-major f16 for k_rnn ----------------
// chunk i (0..63) of col j = Wh[8i..8i+7][j] packed as uint4 (4x half2).
// dst layout: [0,40):   resident  Wres[i*512 + j]
//             [40,64):  streamed  Wstr[(g*512 + j)*4 + c], i = 40+4g+c
// Streamed groups are 64B/thread contiguous and lane-coalesced (4KB/wave).
__global__ void k_wprep(const float* __restrict__ W, uint4* __restrict__ dst) {
  int idx = blockIdx.x * 256 + threadIdx.x;   // 64*512 threads
  int i = idx >> 9;
  int j = idx & 511;
  const float* src = W + (size_t)(512 + i * 8) * 512 + j;  // Wh rows of W (EMB+HID,HID)
  uint32_t u0 = __builtin_bit_cast(uint32_t, __floats2half2_rn(src[0],        src[512]));
  uint32_t u1 = __builtin_bit_cast(uint32_t, __floats2half2_rn(src[1024],     src[1536]));
  uint32_t u2 = __builtin_bit_cast(uint32_t, __floats2half2_rn(src[2048],     src[2560]));
  uint32_t u3 = __builtin_bit_cast(uint32_t, __floats2half2_rn(src[3072],     src[3584]));
  uint4 v; v.x = u0; v.y = u1; v.z = u2; v.w = u3;
  if (i < 40) {
    dst[i * 512 + j] = v;
  } else {
    int ii = i - 40;
    int g = ii >> 2, c = ii & 3;
    dst[40 * 512 + ((size_t)(g * 512 + j) * 4 + c)] = v;
  }
}

// ---------------- f16 MFMA GEMM: C(MxN,f32) = A(MxK,f16) * Bt(NxK,f16)^T + bias ----------------
__global__ __launch_bounds__(256, 2) void k_gemm(
    const __half* __restrict__ A, const __half* __restrict__ Bt,
    const float* __restrict__ bias, float* __restrict__ C,
    int M, int N, int K) {
  __shared__ __align__(16) __half As[128 * 32];
  __shared__ __align__(16) __half Bs[128 * 32];
  const int tid = threadIdx.x;
  const int m0 = blockIdx.x * 128;
  const int n0 = blockIdx.y * 128;
  const int w = tid >> 6;
  const int lane = tid & 63;
  const int wm = (w >> 1) * 64;
  const int wn = (w & 1) * 64;
  const int fr = lane & 15;
  const int q = lane >> 4;
  const int lr = tid >> 2;
  const int lc = tid & 3;
  f4_t acc[4][4];
#pragma unroll
  for (int i = 0; i < 4; ++i)
#pragma unroll
    for (int jj = 0; jj < 4; ++jj) acc[i][jj] = (f4_t)(0.f);

  for (int kk = 0; kk < K; kk += 32) {
    *(uint4*)&As[lr * 32 + lc * 8]        = *(const uint4*)&A[(size_t)(m0 + lr) * K + kk + lc * 8];
    *(uint4*)&As[(64 + lr) * 32 + lc * 8] = *(const uint4*)&A[(size_t)(m0 + 64 + lr) * K + kk + lc * 8];
    *(uint4*)&Bs[lr * 32 + lc * 8]        = *(const uint4*)&Bt[(size_t)(n0 + lr) * K + kk + lc * 8];
    *(uint4*)&Bs[(64 + lr) * 32 + lc * 8] = *(const uint4*)&Bt[(size_t)(n0 + 64 + lr) * K + kk + lc * 8];
    __syncthreads();
    h8_t af[4], bf[4];
#pragma unroll
    for (int i = 0; i < 4; ++i) {
      af[i] = *(const h8_t*)&As[(wm + i * 16 + fr) * 32 + q * 8];
      bf[i] = *(const h8_t*)&Bs[(wn + i * 16 + fr) * 32 + q * 8];
    }
#pragma unroll
    for (int i = 0; i < 4; ++i)
#pragma unroll
      for (int jj = 0; jj < 4; ++jj)
        acc[i][jj] = __builtin_amdgcn_mfma_f32_16x16x32_f16(af[i], bf[jj], acc[i][jj], 0, 0, 0);
    __syncthreads();
  }
#pragma unroll
  for (int i = 0; i < 4; ++i) {
    const int row0 = m0 + wm + i * 16 + q * 4;
#pragma unroll
    for (int jj = 0; jj < 4; ++jj) {
      const int col = n0 + wn + jj * 16 + fr;
      const float bv = bias[col];
#pragma unroll
      for (int r = 0; r < 4; ++r)
        C[(size_t)(row0 + r) * N + col] = acc[i][jj][r] + bv;
    }
  }
}

// ---------------- serial recurrence: 64 blocks x 512 threads ----------------
// One CU per (b,d). Thread = one output column, FULL K (no partial-sum
// exchange, one barrier/step). R0 was LDS-pipe-bound (~2800 cyc/step of LDS
// traffic: 147KB weight streaming + h broadcasts). Fix: weights 40 chunks
// (160 VGPR) register-resident + 24 chunks re-streamed each step from L2
// (the L2 is idle and, with only 64 CUs active, each gets ~4x the per-CU L2
// share). h broadcast (uniform ds_read_b128, ~2cyc) is now the ONLY LDS load.
// Streamed loads staggered 2 groups ahead; sched_barrier(0) pins the stagger
// so the allocator keeps peak live regs ~240 (8 waves -> 256 budget).
#define LOADG(SX, G) do {                                          \
    SX[0] = Wstr[((size_t)((G) * 512 + j)) * 4 + 0];               \
    SX[1] = Wstr[((size_t)((G) * 512 + j)) * 4 + 1];               \
    SX[2] = Wstr[((size_t)((G) * 512 + j)) * 4 + 2];               \
    SX[3] = Wstr[((size_t)((G) * 512 + j)) * 4 + 3];               \
  } while (0)

#define CONS(SX, CB) do {                                          \
    uint4 hv;                                                      \
    hv = hp[(CB) + 0];                                             \
    c0 = fdot2f(hv.x, SX[0].x, c0); c1 = fdot2f(hv.y, SX[0].y, c1);\
    c2 = fdot2f(hv.z, SX[0].z, c2); c3 = fdot2f(hv.w, SX[0].w, c3);\
    hv = hp[(CB) + 1];                                             \
    c0 = fdot2f(hv.x, SX[1].x, c0); c1 = fdot2f(hv.y, SX[1].y, c1);\
    c2 = fdot2f(hv.z, SX[1].z, c2); c3 = fdot2f(hv.w, SX[1].w, c3);\
    hv = hp[(CB) + 2];                                             \
    c0 = fdot2f(hv.x, SX[2].x, c0); c1 = fdot2f(hv.y, SX[2].y, c1);\
    c2 = fdot2f(hv.z, SX[2].z, c2); c3 = fdot2f(hv.w, SX[2].w, c3);\
    hv = hp[(CB) + 3];                                             \
    c0 = fdot2f(hv.x, SX[3].x, c0); c1 = fdot2f(hv.y, SX[3].y, c1);\
    c2 = fdot2f(hv.z, SX[3].z, c2); c3 = fdot2f(hv.w, SX[3].w, c3);\
  } while (0)

__global__ __launch_bounds__(512, 1) void k_rnn(
    const uint4* __restrict__ Wp_f, const uint4* __restrict__ Wp_b,
    const float* __restrict__ A_f, const float* __restrict__ A_b,
    __half* __restrict__ bi) {
  __shared__ __align__(16) __half hbuf[2][HIDN];   // double-buffered h, 2 KB
  const int j = threadIdx.x;                       // 512 threads = 512 columns
  const int d = blockIdx.x & 1;
  const int b = blockIdx.x >> 1;
  const uint4* Wp = d ? Wp_b : Wp_f;
  const float* A = (d ? A_b : A_f) + (size_t)b * SEQ * HIDN;
  __half* bip = bi + (size_t)b * SEQ * 1024 + d * HIDN + j;
  const uint4* Wres = Wp;                          // [40][512]
  const uint4* Wstr = Wp + 40 * 512;               // [6][512][4]

  uint4 wv[40];                                    // resident weights: 160 VGPRs
#pragma unroll
  for (int i = 0; i < 40; ++i) wv[i] = Wres[i * 512 + j];

  hbuf[0][j] = __float2half(0.f);
  __syncthreads();

  const int tstep = d ? -1 : 1;
  int tt = d ? (SEQ - 1) : 0;
  float a_next = A[(size_t)tt * HIDN + j];
  int cur = 0;
#pragma unroll 1
  for (int s = 0; s < SEQ; ++s) {
    float a_cur = a_next;
    int tn = tt + tstep;
    tn = tn < 0 ? 0 : (tn > SEQ - 1 ? SEQ - 1 : tn);
    a_next = A[(size_t)tn * HIDN + j];             // prefetch next additive term
    const uint4* hp = (const uint4*)hbuf[cur];     // block-uniform -> broadcast reads

    uint4 s0[4], s1[4], s2[4], s3[4], s4[4], s5[4];
    LOADG(s0, 0);
    LOADG(s1, 1);
    __builtin_amdgcn_sched_barrier(0);

    float c0 = 0.f, c1 = 0.f, c2 = 0.f, c3 = 0.f;
#pragma unroll
    for (int i = 0; i < 40; ++i) {                 // register-resident chunks
      uint4 hv = hp[i];
      c0 = fdot2f(hv.x, wv[i].x, c0);
      c1 = fdot2f(hv.y, wv[i].y, c1);
      c2 = fdot2f(hv.z, wv[i].z, c2);
      c3 = fdot2f(hv.w, wv[i].w, c3);
    }
    __builtin_amdgcn_sched_barrier(0);
    CONS(s0, 40); LOADG(s2, 2);
    __builtin_amdgcn_sched_barrier(0);
    CONS(s1, 44); LOADG(s3, 3);
    __builtin_amdgcn_sched_barrier(0);
    CONS(s2, 48); LOADG(s4, 4);
    __builtin_amdgcn_sched_barrier(0);
    CONS(s3, 52); LOADG(s5, 5);
    __builtin_amdgcn_sched_barrier(0);
    CONS(s4, 56);
    CONS(s5, 60);

    float p = (c0 + c1) + (c2 + c3) + a_cur;
    float ap = fabsf(p);
    float e = __expf(2.f * ap);
    float th = 1.f - 2.f * __builtin_amdgcn_rcpf(e + 1.f);  // tanh(|p|)
    float h = copysignf(th, p);
    __half hh = __float2half(h);
    hbuf[cur ^ 1][j] = hh;
    bip[(size_t)tt * 1024] = hh;
    __syncthreads();                               // single barrier per step
    cur ^= 1;
    tt += tstep;
  }
}

extern "C" void kernel_launch(void* const* d_in, const int* in_sizes, int n_in,
                              void* d_out, int out_size, void* d_ws, size_t ws_size,
                              hipStream_t stream) {
  const float* input_seq = (const float*)d_in[0];  // (32,512,512)
  const float* W_f = (const float*)d_in[1];        // (1024,512)
  const float* b_f = (const float*)d_in[2];
  const float* W_b = (const float*)d_in[3];
  const float* b_b = (const float*)d_in[4];
  const float* W_o = (const float*)d_in[5];        // (1024,512)
  const float* b_o = (const float*)d_in[6];
  float* out = (float*)d_out;

  char* ws = (char*)d_ws;
  __half* Xh    = (__half*)(ws);                    // 16 MB  (16384x512 f16)
  float*  A_f   = (float*)(ws + 16777216);          // 32 MB
  float*  A_b   = (float*)(ws + 50331648);          // 32 MB
  __half* bi    = (__half*)(ws + 83886080);         // 32 MB  (16384x1024 f16)
  __half* WxT_f = (__half*)(ws + 117440512);        // 512 KB
  __half* WxT_b = (__half*)(ws + 117964800);
  uint4*  Wp_f  = (uint4*)(ws + 118489088);         // 512 KB chunk-major Wh_f
  uint4*  Wp_b  = (uint4*)(ws + 119013376);         // 512 KB chunk-major Wh_b
  __half* WoT   = (__half*)(ws + 119537664);        // 1 MB

  k_cvt<<<8192, 256, 0, stream>>>((const float4*)input_seq, (__half2*)Xh, 2097152);
  dim3 tb(32, 8);
  k_transpose_cvt<<<dim3(16, 16), tb, 0, stream>>>(W_f, WxT_f, 512, 512);
  k_transpose_cvt<<<dim3(16, 16), tb, 0, stream>>>(W_b, WxT_b, 512, 512);
  k_transpose_cvt<<<dim3(16, 32), tb, 0, stream>>>(W_o, WoT, 1024, 512);
  k_wprep<<<128, 256, 0, stream>>>(W_f, Wp_f);
  k_wprep<<<128, 256, 0, stream>>>(W_b, Wp_b);

  k_gemm<<<dim3(128, 4), 256, 0, stream>>>(Xh, WxT_f, b_f, A_f, 16384, 512, 512);
  k_gemm<<<dim3(128, 4), 256, 0, stream>>>(Xh, WxT_b, b_b, A_b, 16384, 512, 512);

  k_rnn<<<64, 512, 0, stream>>>(Wp_f, Wp_b, A_f, A_b, bi);

  k_gemm<<<dim3(128, 4), 256, 0, stream>>>(bi, WoT, b_o, out, 16384, 512, 1024);
}